// Round 4
// baseline (261.476 us; speedup 1.0000x reference)
//
#include <hip/hip_runtime.h>

typedef unsigned int u32;
typedef unsigned short u16;
typedef __attribute__((ext_vector_type(8))) short short8;
typedef __attribute__((ext_vector_type(4))) float floatx4;

#define NB 4
#define NF 5
#define NN 2048
#define NDM 256
#define NBF (NB*NF)          // 20
#define NBFN (NBF*NN)        // 40960
#define NBFD (NBF*NDM)       // 5120

#define AS1 __attribute__((address_space(1)))
#define AS3 __attribute__((address_space(3)))

// Static device scratch; everything read is fully rewritten each call.
__device__ u16    g_xb[(size_t)NBF*NN*NDM];   // bf16 copy of x
__device__ u16    g_yb[(size_t)NBF*NN*NDM];   // bf16 copy of y
__device__ float  g_a2[NBFN];                 // row sumsq of x
__device__ float  g_b2[NBFN];                 // row sumsq of y
__device__ float  g_rpart[(size_t)8*NBFN];    // partial row mins: plane = jq*2+wc
__device__ float  g_cpart[(size_t)32*NBFN];   // partial col mins: plane = i0t*2+wr
__device__ float  g_pmn[2][(size_t)32*NBFD];  // per-chunk partial min over n
__device__ float  g_pmx[2][(size_t)32*NBFD];  // per-chunk partial max over n
__device__ float  g_bfsum[2*NBF];             // per-(dir,bf) sum of mins (atomicAdd)
__device__ float4 g_coef[NBFD];               // sx, ox, sy, oy per (bf,d)

__device__ __forceinline__ u16 cvt_bf16(float f){    // RNE
  u32 b = __float_as_uint(f);
  return (u16)((b + 0x7FFFu + ((b >> 16) & 1u)) >> 16);
}
__device__ __forceinline__ float bf2f(short v){
  return __uint_as_float(((u32)(u16)v) << 16);
}
__device__ __forceinline__ void load16(const void* g, void* l){
  __builtin_amdgcn_global_load_lds((AS1 const void*)g, (AS3 void*)l, 16, 0, 0);
}

// K1: single pass over x,y: bf16 convert + per-(bf,d) partial min/max +
// row sumsq via LDS matrix reduction (NO serialized shfl chains in the
// main loop — every iteration is independent). Block = 64 rows.
__global__ void __launch_bounds__(256) k_prep(const float* __restrict__ x,
                                              const float* __restrict__ y){
  __shared__ float sS[64][65];                // per-(row,lane) sumsq partials
  __shared__ float sp[4][64];                 // stage-2 partials
  __shared__ float4 smn[4][64], smx[4][64];
  int bi = blockIdx.x;                        // 2 * 20 * 32 = 1280
  if (bi == 0 && threadIdx.x < 2*NBF) g_bfsum[threadIdx.x] = 0.f;
  int tensor = bi >= (NBF*32); int rem = bi - tensor*(NBF*32);
  int bf = rem >> 5; int chunk = rem & 31;
  size_t rbase = (size_t)bf*NN + (size_t)chunk*64;
  const float* src = (tensor ? y : x) + rbase*NDM;
  u16*  dst  = (tensor ? g_yb : g_xb) + rbase*NDM;
  float* sums = (tensor ? g_b2 : g_a2) + bf*NN + chunk*64;
  int w = threadIdx.x >> 6, l = threadIdx.x & 63;

  float4 vmn = make_float4(INFINITY,INFINITY,INFINITY,INFINITY);
  float4 vmx = make_float4(-INFINITY,-INFINITY,-INFINITY,-INFINITY);
  for (int i = 0; i < 16; ++i){
    int row = w + 4*i;
    float4 v = ((const float4*)(src + (size_t)row*NDM))[l];
    sS[row][l] = v.x*v.x + v.y*v.y + v.z*v.z + v.w*v.w;
    ((ushort4*)(dst + (size_t)row*NDM))[l] =
        make_ushort4(cvt_bf16(v.x), cvt_bf16(v.y), cvt_bf16(v.z), cvt_bf16(v.w));
    vmn.x = fminf(vmn.x, v.x); vmn.y = fminf(vmn.y, v.y);
    vmn.z = fminf(vmn.z, v.z); vmn.w = fminf(vmn.w, v.w);
    vmx.x = fmaxf(vmx.x, v.x); vmx.y = fmaxf(vmx.y, v.y);
    vmx.z = fmaxf(vmx.z, v.z); vmx.w = fmaxf(vmx.w, v.w);
  }
  smn[w][l] = vmn; smx[w][l] = vmx;
  __syncthreads();
  // row-sumsq reduce, stage 1: 4 threads per row sum 16 lanes each.
  {
    int row = threadIdx.x & 63, q = threadIdx.x >> 6;
    float p = 0.f;
    #pragma unroll
    for (int i = 0; i < 16; ++i) p += sS[row][q*16 + i];
    sp[q][row] = p;
  }
  __syncthreads();
  if (threadIdx.x < 64)
    sums[threadIdx.x] = sp[0][threadIdx.x] + sp[1][threadIdx.x]
                      + sp[2][threadIdx.x] + sp[3][threadIdx.x];
  if (w == 0){
    float4 a = smn[0][l], b_ = smn[1][l], c = smn[2][l], d = smn[3][l];
    float4 e = smx[0][l], f = smx[1][l], g = smx[2][l], h = smx[3][l];
    float4 mn4 = make_float4(fminf(fminf(a.x,b_.x), fminf(c.x,d.x)),
                             fminf(fminf(a.y,b_.y), fminf(c.y,d.y)),
                             fminf(fminf(a.z,b_.z), fminf(c.z,d.z)),
                             fminf(fminf(a.w,b_.w), fminf(c.w,d.w)));
    float4 mx4 = make_float4(fmaxf(fmaxf(e.x,f.x), fmaxf(g.x,h.x)),
                             fmaxf(fmaxf(e.y,f.y), fmaxf(g.y,h.y)),
                             fmaxf(fmaxf(e.z,f.z), fmaxf(g.z,h.z)),
                             fmaxf(fmaxf(e.w,f.w), fmaxf(g.w,h.w)));
    ((float4*)&g_pmn[tensor][(size_t)chunk*NBFD + bf*NDM])[l] = mn4;
    ((float4*)&g_pmx[tensor][(size_t)chunk*NBFD + bf*NDM])[l] = mx4;
  }
}

// K2: GEMM. R3 lesson: counted-vmcnt tri-buffer regressed (runtime buf
// indexing + no overlap realized); XCD swizzle worked (FETCH 62->24.5MB).
// R4 change: 2x2 wave split. Waves form a 2x2 grid; each wave owns
// 64 rows x 64 cols of the 128x128 jj-chunk. Per phase each wave reads
// HALF of B from LDS (8 ds_read_b128 vs 16) for the same 32 MFMA ->
// block LDS-read traffic per phase halves (768->384 cy of the ~2070-cy
// critical path), MFMA:LDS ratio 2:1 -> 4:1. A register-resident for 64
// rows (af[4][8] = 128 VGPR); a2 loads scoped to the jj-epilogue to keep
// peak VGPR ~240 < 256 cap of (256,2). Plain 2-barrier double-buffer
// (proven), XCD panel-major swizzle kept.
__global__ void __launch_bounds__(256, 2) k_gemm(){
  __shared__ u16 Bs[2][128*64];               // 2 x 16 KB: [buf][row*64 + k]
  __shared__ float b2s[512];                  // b2 for the j-quarter
  const int orig = blockIdx.x;                // 0..1279
  const int work = (orig & 7)*160 + (orig >> 3);  // XCD gets contiguous 160
  const int bf  = work >> 6;                  // panel-major: (bf,jq) outer
  const int jq  = (work >> 4) & 3;
  const int i0t = work & 15;
  const int i0  = i0t * 128;
  const int t = threadIdx.x;
  const int w = t >> 6, l = t & 63;
  const int wr = w >> 1, wc = w & 1;          // 2x2 wave grid
  const int quad = l >> 4, c16 = l & 15;
  const u16* xb = g_xb + (size_t)bf * NN * NDM;
  const u16* yb = g_yb + (size_t)bf * NN * NDM;

  const float* b2 = g_b2 + bf*NN;
  ((float2*)b2s)[t] = ((const float2*)(b2 + jq*512))[t];

  // A fragments: this wave's 64 rows x full K=256.
  short8 af[4][8];
  #pragma unroll
  for (int mb = 0; mb < 4; ++mb){
    const u16* rp = xb + (size_t)(i0 + wr*64 + mb*16 + c16) * NDM + quad*8;
    #pragma unroll
    for (int ks = 0; ks < 8; ++ks)
      af[mb][ks] = *(const short8*)(rp + ks*32);
  }

  float rm[4][4];
  #pragma unroll
  for (int mb = 0; mb < 4; ++mb)
    #pragma unroll
    for (int r = 0; r < 4; ++r) rm[mb][r] = INFINITY;

  // stage one 128-row x 64-k slice (16 KB). it = jj*4 + s.
  auto stage = [&](int it, int bb){
    const int j0 = jq*512 + (it >> 2)*128;
    const int ko = (it & 3)*64;               // k offset within K=256
    #pragma unroll
    for (int q = 0; q < 4; ++q){
      const int rb = q*32 + w*8;              // wave-uniform row base
      const int row = rb + (l >> 3);          // 8 rows per load16
      const int c = (l & 7) ^ ((l >> 3) & 7); // pre-swizzled source chunk
      load16(yb + (size_t)(j0 + row)*NDM + ko + c*8,
             &Bs[bb][rb*64]);
    }
  };

  int buf = 0;
  stage(0, 0);
  for (int jj = 0; jj < 4; ++jj){
    const int j0 = jq*512 + jj*128;
    floatx4 acc[4][4] = {};
    #pragma unroll
    for (int s = 0; s < 4; ++s){
      __syncthreads();                        // drains aged prefetch
      const int nit = jj*4 + s + 1;
      if (nit < 16) stage(nit, buf ^ 1);
      #pragma unroll
      for (int ksl = 0; ksl < 2; ++ksl){
        const int lc = ((ksl*4 + quad) ^ (c16 & 7)) * 8;   // de-swizzle
        short8 bq[4];
        #pragma unroll
        for (int nb = 0; nb < 4; ++nb)
          bq[nb] = *(const short8*)&Bs[buf][(wc*64 + nb*16 + c16)*64 + lc];
        #pragma unroll
        for (int mb = 0; mb < 4; ++mb)
          #pragma unroll
          for (int nb = 0; nb < 4; ++nb)
            acc[mb][nb] = __builtin_amdgcn_mfma_f32_16x16x32_bf16(af[mb][s*2+ksl], bq[nb], acc[mb][nb], 0, 0, 0);
      }
      buf ^= 1;
    }
    // epilogue: a2 loaded here (scoped) to keep inner-loop VGPR peak down.
    float a2r[4][4];
    {
      const float* a2 = g_a2 + bf*NN + i0 + wr*64;
      #pragma unroll
      for (int mb = 0; mb < 4; ++mb)
        #pragma unroll
        for (int r = 0; r < 4; ++r)
          a2r[mb][r] = a2[mb*16 + quad*4 + r];
    }
    float bcol[4], colm[4];
    #pragma unroll
    for (int nb = 0; nb < 4; ++nb){
      bcol[nb] = b2s[jj*128 + wc*64 + nb*16 + c16];
      colm[nb] = INFINITY;
    }
    #pragma unroll
    for (int mb = 0; mb < 4; ++mb)
      #pragma unroll
      for (int r = 0; r < 4; ++r)
        #pragma unroll
        for (int nb = 0; nb < 4; ++nb){
          float dd = a2r[mb][r] + bcol[nb] - 2.0f * acc[mb][nb][r];
          rm[mb][r] = fminf(rm[mb][r], dd);
          colm[nb] = fminf(colm[nb], dd);
        }
    #pragma unroll
    for (int nb = 0; nb < 4; ++nb){
      float cm = colm[nb];
      cm = fminf(cm, __shfl_xor(cm, 16, 64));
      cm = fminf(cm, __shfl_xor(cm, 32, 64));
      if (quad == 0)
        g_cpart[(size_t)(i0t*2 + wr)*NBFN + bf*NN + j0 + wc*64 + nb*16 + c16] = cm;
    }
  }
  #pragma unroll
  for (int mb = 0; mb < 4; ++mb)
    #pragma unroll
    for (int r = 0; r < 4; ++r){
      float v = rm[mb][r];
      v = fminf(v, __shfl_xor(v, 1, 64));
      v = fminf(v, __shfl_xor(v, 2, 64));
      v = fminf(v, __shfl_xor(v, 4, 64));
      v = fminf(v, __shfl_xor(v, 8, 64));
      if (c16 == 0)
        g_rpart[(size_t)(jq*2 + wc)*NBFN + bf*NN + i0 + wr*64 + mb*16 + quad*4 + r] = v;
    }
}

// K3: hierarchical reduce of partial-min planes -> per-bf sums (atomicAdd).
__global__ void __launch_bounds__(256) k_weight(){
  int bf = blockIdx.x >> 3;
  int chunk = blockIdx.x & 7;
  int i = chunk*256 + threadIdx.x;            // row index in [0,2048)
  size_t base = (size_t)bf*NN + i;
  float m = INFINITY, c = INFINITY;
  #pragma unroll
  for (int p = 0; p < 8; ++p)  m = fminf(m, g_rpart[(size_t)p*NBFN + base]);
  #pragma unroll
  for (int p = 0; p < 32; ++p) c = fminf(c, g_cpart[(size_t)p*NBFN + base]);
  float srow = m, scol = c;
  #pragma unroll
  for (int mm = 1; mm < 64; mm <<= 1){
    srow += __shfl_xor(srow, mm, 64);
    scol += __shfl_xor(scol, mm, 64);
  }
  __shared__ float pr[4], pcn[4];
  int w = threadIdx.x >> 6, l = threadIdx.x & 63;
  if (l == 0){ pr[w] = srow; pcn[w] = scol; }
  __syncthreads();
  if (threadIdx.x == 0){
    atomicAdd(&g_bfsum[bf],       pr[0]+pr[1]+pr[2]+pr[3]);
    atomicAdd(&g_bfsum[NBF + bf], pcn[0]+pcn[1]+pcn[2]+pcn[3]);
  }
}

// K4: fold weights + min/max partials into per-(bf,d) affine coefficients.
__global__ void k_coef(){
  int idx = blockIdx.x * 256 + threadIdx.x;   // < NBFD
  int bf = idx >> 8;
  int b = bf / NF;
  float swx = 0.f, swy = 0.f;
  #pragma unroll
  for (int f = 0; f < NF; ++f){
    swx += g_bfsum[b*NF + f];
    swy += g_bfsum[NBF + b*NF + f];
  }
  float wx = 1.0f / (1.0f + swx * (1.0f/(NF*NN)));
  float wy = 1.0f / (1.0f + swy * (1.0f/(NF*NN)));
  float mnx = INFINITY, mxx = -INFINITY, mny = INFINITY, mxy = -INFINITY;
  #pragma unroll
  for (int c = 0; c < 32; ++c){
    mnx = fminf(mnx, g_pmn[0][(size_t)c*NBFD + idx]);
    mxx = fmaxf(mxx, g_pmx[0][(size_t)c*NBFD + idx]);
    mny = fminf(mny, g_pmn[1][(size_t)c*NBFD + idx]);
    mxy = fmaxf(mxy, g_pmx[1][(size_t)c*NBFD + idx]);
  }
  float sx = wx / (mxx - mnx), sy = wy / (mxy - mny);
  g_coef[idx] = make_float4(sx, -sx * mnx, sy, -sy * mny);
}

// K5: out = sx*xb + ox + sy*yb + oy from the L3-hot bf16 copies (halves
// read bytes vs fp32 x,y). One thread per 8 elements; flat 5120-block grid.
__global__ void __launch_bounds__(256) k_out(floatx4* __restrict__ out){
  size_t e0 = ((size_t)blockIdx.x * 256 + threadIdx.x) * 8;  // elem index
  int bf = (int)(e0 >> 19);                   // NN*NDM = 2^19
  int d0 = (int)(e0 & 255);
  short8 xv = *(const short8*)&g_xb[e0];
  short8 yv = *(const short8*)&g_yb[e0];
  const float4* cf = &g_coef[bf*256 + d0];
  floatx4 o0, o1;
  #pragma unroll
  for (int j = 0; j < 4; ++j){
    float4 c = cf[j];
    o0[j] = c.x * bf2f(xv[j]) + c.y + c.z * bf2f(yv[j]) + c.w;
  }
  #pragma unroll
  for (int j = 0; j < 4; ++j){
    float4 c = cf[4 + j];
    o1[j] = c.x * bf2f(xv[4 + j]) + c.y + c.z * bf2f(yv[4 + j]) + c.w;
  }
  __builtin_nontemporal_store(o0, &out[e0 >> 2]);
  __builtin_nontemporal_store(o1, &out[(e0 >> 2) + 1]);
}

extern "C" void kernel_launch(void* const* d_in, const int* in_sizes, int n_in,
                              void* d_out, int out_size, void* d_ws, size_t ws_size,
                              hipStream_t stream) {
  const float* x = (const float*)d_in[0];
  const float* y = (const float*)d_in[1];
  (void)d_ws; (void)ws_size; (void)in_sizes; (void)n_in; (void)out_size;

  k_prep  <<<dim3(1280), dim3(256), 0, stream>>>(x, y);
  k_gemm  <<<dim3(1280), dim3(256), 0, stream>>>();
  k_weight<<<dim3(160),  dim3(256), 0, stream>>>();
  k_coef  <<<dim3(20),   dim3(256), 0, stream>>>();
  k_out   <<<dim3(5120), dim3(256), 0, stream>>>((floatx4*)d_out);
}

// Round 5
// 215.408 us; speedup vs baseline: 1.2139x; 1.2139x over previous
//
#include <hip/hip_runtime.h>

typedef unsigned int u32;
typedef unsigned short u16;
typedef __attribute__((ext_vector_type(8))) short short8;
typedef __attribute__((ext_vector_type(4))) float floatx4;

#define NB 4
#define NF 5
#define NN 2048
#define NDM 256
#define NBF (NB*NF)          // 20
#define NBFN (NBF*NN)        // 40960
#define NBFD (NBF*NDM)       // 5120

#define AS1 __attribute__((address_space(1)))
#define AS3 __attribute__((address_space(3)))

// Static device scratch; everything read is fully rewritten each call.
__device__ u16    g_xb[(size_t)NBF*NN*NDM];   // bf16 copy of x
__device__ u16    g_yb[(size_t)NBF*NN*NDM];   // bf16 copy of y
__device__ float  g_a2[NBFN];                 // row sumsq of x
__device__ float  g_b2[NBFN];                 // row sumsq of y
__device__ float  g_rpart[(size_t)4*NBFN];    // partial row mins: plane = jq
__device__ float  g_cpart[(size_t)64*NBFN];   // partial col mins: plane = i0t*4+w
__device__ float  g_pmn[2][(size_t)32*NBFD];  // per-chunk partial min over n
__device__ float  g_pmx[2][(size_t)32*NBFD];  // per-chunk partial max over n
__device__ float  g_bfsum[2*NBF];             // per-(dir,bf) sum of mins (atomicAdd)
__device__ float4 g_coef[NBFD];               // sx, ox, sy, oy per (bf,d)

__device__ __forceinline__ u16 cvt_bf16(float f){    // RNE
  u32 b = __float_as_uint(f);
  return (u16)((b + 0x7FFFu + ((b >> 16) & 1u)) >> 16);
}
__device__ __forceinline__ float bf2f(short v){
  return __uint_as_float(((u32)(u16)v) << 16);
}
__device__ __forceinline__ void load16(const void* g, void* l){
  __builtin_amdgcn_global_load_lds((AS1 const void*)g, (AS3 void*)l, 16, 0, 0);
}

// K1: single pass over x,y: bf16 convert + per-(bf,d) partial min/max +
// row sumsq via LDS matrix reduction (NO serialized shfl chains in the
// main loop — every iteration is independent). Block = 64 rows.
__global__ void __launch_bounds__(256) k_prep(const float* __restrict__ x,
                                              const float* __restrict__ y){
  __shared__ float sS[64][65];                // per-(row,lane) sumsq partials
  __shared__ float sp[4][64];                 // stage-2 partials
  __shared__ float4 smn[4][64], smx[4][64];
  int bi = blockIdx.x;                        // 2 * 20 * 32 = 1280
  if (bi == 0 && threadIdx.x < 2*NBF) g_bfsum[threadIdx.x] = 0.f;
  int tensor = bi >= (NBF*32); int rem = bi - tensor*(NBF*32);
  int bf = rem >> 5; int chunk = rem & 31;
  size_t rbase = (size_t)bf*NN + (size_t)chunk*64;
  const float* src = (tensor ? y : x) + rbase*NDM;
  u16*  dst  = (tensor ? g_yb : g_xb) + rbase*NDM;
  float* sums = (tensor ? g_b2 : g_a2) + bf*NN + chunk*64;
  int w = threadIdx.x >> 6, l = threadIdx.x & 63;

  float4 vmn = make_float4(INFINITY,INFINITY,INFINITY,INFINITY);
  float4 vmx = make_float4(-INFINITY,-INFINITY,-INFINITY,-INFINITY);
  for (int i = 0; i < 16; ++i){
    int row = w + 4*i;
    float4 v = ((const float4*)(src + (size_t)row*NDM))[l];
    sS[row][l] = v.x*v.x + v.y*v.y + v.z*v.z + v.w*v.w;
    ((ushort4*)(dst + (size_t)row*NDM))[l] =
        make_ushort4(cvt_bf16(v.x), cvt_bf16(v.y), cvt_bf16(v.z), cvt_bf16(v.w));
    vmn.x = fminf(vmn.x, v.x); vmn.y = fminf(vmn.y, v.y);
    vmn.z = fminf(vmn.z, v.z); vmn.w = fminf(vmn.w, v.w);
    vmx.x = fmaxf(vmx.x, v.x); vmx.y = fmaxf(vmx.y, v.y);
    vmx.z = fmaxf(vmx.z, v.z); vmx.w = fmaxf(vmx.w, v.w);
  }
  smn[w][l] = vmn; smx[w][l] = vmx;
  __syncthreads();
  // row-sumsq reduce, stage 1: 4 threads per row sum 16 lanes each.
  {
    int row = threadIdx.x & 63, q = threadIdx.x >> 6;
    float p = 0.f;
    #pragma unroll
    for (int i = 0; i < 16; ++i) p += sS[row][q*16 + i];
    sp[q][row] = p;
  }
  __syncthreads();
  if (threadIdx.x < 64)
    sums[threadIdx.x] = sp[0][threadIdx.x] + sp[1][threadIdx.x]
                      + sp[2][threadIdx.x] + sp[3][threadIdx.x];
  if (w == 0){
    float4 a = smn[0][l], b_ = smn[1][l], c = smn[2][l], d = smn[3][l];
    float4 e = smx[0][l], f = smx[1][l], g = smx[2][l], h = smx[3][l];
    float4 mn4 = make_float4(fminf(fminf(a.x,b_.x), fminf(c.x,d.x)),
                             fminf(fminf(a.y,b_.y), fminf(c.y,d.y)),
                             fminf(fminf(a.z,b_.z), fminf(c.z,d.z)),
                             fminf(fminf(a.w,b_.w), fminf(c.w,d.w)));
    float4 mx4 = make_float4(fmaxf(fmaxf(e.x,f.x), fmaxf(g.x,h.x)),
                             fmaxf(fmaxf(e.y,f.y), fmaxf(g.y,h.y)),
                             fmaxf(fmaxf(e.z,f.z), fmaxf(g.z,h.z)),
                             fmaxf(fmaxf(e.w,f.w), fmaxf(g.w,h.w)));
    ((float4*)&g_pmn[tensor][(size_t)chunk*NBFD + bf*NDM])[l] = mn4;
    ((float4*)&g_pmx[tensor][(size_t)chunk*NBFD + bf*NDM])[l] = mx4;
  }
}

// K2: GEMM. R4 lesson: 2x2 wave split needs af=128 VGPR; allocator steps
// 64/128/256 and clamped to 128 -> af spilled (WRITE 11->68MB, 109us).
// Per-wave A residency is capped at ~64 VGPR (32 rows) at this occupancy.
// R5 = exact R0 structure (BK=128, 8 phases, plain-syncthreads dbuf,
// 1-D row-split waves, af[2][8], proven 124 VGPR no-spill, 65.9us) plus
// ONE delta: the R3-proven XCD panel-major swizzle (FETCH 62->24.5MB).
// Mechanism: staging loads become L2-hits (~200-400cy vs ~900cy HBM), so
// the per-phase barrier vmcnt-drain (issued ~1 phase = ~2000cy earlier)
// is fully covered. Blocks with orig%8==const land on one XCD and map to
// 16 consecutive works sharing one 256KB B-panel.
__global__ void __launch_bounds__(256, 2) k_gemm(){
  __shared__ u16 Bs[2][128*128];              // 2 x 32 KB: [buf][row*128 + k]
  __shared__ float b2s[512];                  // b2 for the j-quarter
  const int orig = blockIdx.x;                // 0..1279
  const int work = (orig & 7)*160 + (orig >> 3);  // XCD gets contiguous 160
  const int bf  = work >> 6;                  // panel-major: (bf,jq) outer
  const int jq  = (work >> 4) & 3;            // cols jq*512 .. +511
  const int i0t = work & 15;
  const int i0  = i0t * 128;
  const int t = threadIdx.x;
  const int w = t >> 6, l = t & 63;
  const int quad = l >> 4, c16 = l & 15;
  const int wrow = w * 32;                    // wave's 32-row slice
  const u16* xb = g_xb + (size_t)bf * NN * NDM;
  const u16* yb = g_yb + (size_t)bf * NN * NDM;

  const float* b2 = g_b2 + bf*NN;
  ((float2*)b2s)[t] = ((const float2*)(b2 + jq*512))[t];

  short8 af[2][8];
  #pragma unroll
  for (int mb = 0; mb < 2; ++mb){
    const u16* rp = xb + (size_t)(i0 + wrow + mb*16 + c16) * NDM + quad*8;
    #pragma unroll
    for (int ks = 0; ks < 8; ++ks)
      af[mb][ks] = *(const short8*)(rp + ks*32);
  }
  const float* a2 = g_a2 + bf*NN + i0 + wrow;
  float a2r[2][4];
  #pragma unroll
  for (int mb = 0; mb < 2; ++mb)
    #pragma unroll
    for (int r = 0; r < 4; ++r)
      a2r[mb][r] = a2[mb*16 + quad*4 + r];

  float rm[2][4];
  #pragma unroll
  for (int mb = 0; mb < 2; ++mb)
    #pragma unroll
    for (int r = 0; r < 4; ++r) rm[mb][r] = INFINITY;

  auto stage = [&](int jt, int h, int bb){
    const int j0 = jq*512 + jt*128;
    #pragma unroll
    for (int q = 0; q < 8; ++q){
      const int row = q*16 + w*4 + (l >> 4);  // 0..127
      const int c = (l & 15) ^ (row & 15);
      load16(yb + (size_t)(j0 + row)*NDM + h*128 + c*8,
             &Bs[bb][(q*16 + w*4)*128]);
    }
  };

  int buf = 0;
  stage(0, 0, 0);
  for (int jj = 0; jj < 4; ++jj){
    const int j0 = jq*512 + jj*128;
    floatx4 acc[2][8] = {};
    #pragma unroll
    for (int h = 0; h < 2; ++h){
      __syncthreads();                        // drains aged prefetch
      const int nit = jj*2 + h + 1;
      if (nit < 8) stage(nit >> 1, nit & 1, buf ^ 1);
      #pragma unroll
      for (int ksl = 0; ksl < 4; ++ksl){
        const int lc = ((ksl*4 + quad) ^ c16) * 8;   // de-swizzle
        short8 bq[8];
        #pragma unroll
        for (int nb = 0; nb < 8; ++nb)
          bq[nb] = *(const short8*)&Bs[buf][(nb*16 + c16)*128 + lc];
        #pragma unroll
        for (int mb = 0; mb < 2; ++mb)
          #pragma unroll
          for (int nb = 0; nb < 8; ++nb)
            acc[mb][nb] = __builtin_amdgcn_mfma_f32_16x16x32_bf16(af[mb][h*4+ksl], bq[nb], acc[mb][nb], 0, 0, 0);
      }
      buf ^= 1;
    }
    float bcol[8], colm[8];
    #pragma unroll
    for (int nb = 0; nb < 8; ++nb){
      bcol[nb] = b2s[jj*128 + nb*16 + c16];
      colm[nb] = INFINITY;
    }
    #pragma unroll
    for (int mb = 0; mb < 2; ++mb)
      #pragma unroll
      for (int r = 0; r < 4; ++r)
        #pragma unroll
        for (int nb = 0; nb < 8; ++nb){
          float dd = a2r[mb][r] + bcol[nb] - 2.0f * acc[mb][nb][r];
          rm[mb][r] = fminf(rm[mb][r], dd);
          colm[nb] = fminf(colm[nb], dd);
        }
    #pragma unroll
    for (int nb = 0; nb < 8; ++nb){
      float cm = colm[nb];
      cm = fminf(cm, __shfl_xor(cm, 16, 64));
      cm = fminf(cm, __shfl_xor(cm, 32, 64));
      if (quad == 0)
        g_cpart[(size_t)(i0t*4 + w)*NBFN + bf*NN + j0 + nb*16 + c16] = cm;
    }
  }
  #pragma unroll
  for (int mb = 0; mb < 2; ++mb)
    #pragma unroll
    for (int r = 0; r < 4; ++r){
      float v = rm[mb][r];
      v = fminf(v, __shfl_xor(v, 1, 64));
      v = fminf(v, __shfl_xor(v, 2, 64));
      v = fminf(v, __shfl_xor(v, 4, 64));
      v = fminf(v, __shfl_xor(v, 8, 64));
      if (c16 == 0)
        g_rpart[(size_t)jq*NBFN + bf*NN + i0 + wrow + mb*16 + quad*4 + r] = v;
    }
}

// K3: hierarchical reduce of partial-min planes -> per-bf sums (atomicAdd).
__global__ void __launch_bounds__(256) k_weight(){
  int bf = blockIdx.x >> 3;
  int chunk = blockIdx.x & 7;
  int i = chunk*256 + threadIdx.x;            // row index in [0,2048)
  size_t base = (size_t)bf*NN + i;
  float m = INFINITY, c = INFINITY;
  #pragma unroll
  for (int p = 0; p < 4; ++p)  m = fminf(m, g_rpart[(size_t)p*NBFN + base]);
  #pragma unroll
  for (int p = 0; p < 64; ++p) c = fminf(c, g_cpart[(size_t)p*NBFN + base]);
  float srow = m, scol = c;
  #pragma unroll
  for (int mm = 1; mm < 64; mm <<= 1){
    srow += __shfl_xor(srow, mm, 64);
    scol += __shfl_xor(scol, mm, 64);
  }
  __shared__ float pr[4], pcn[4];
  int w = threadIdx.x >> 6, l = threadIdx.x & 63;
  if (l == 0){ pr[w] = srow; pcn[w] = scol; }
  __syncthreads();
  if (threadIdx.x == 0){
    atomicAdd(&g_bfsum[bf],       pr[0]+pr[1]+pr[2]+pr[3]);
    atomicAdd(&g_bfsum[NBF + bf], pcn[0]+pcn[1]+pcn[2]+pcn[3]);
  }
}

// K4: fold weights + min/max partials into per-(bf,d) affine coefficients.
__global__ void k_coef(){
  int idx = blockIdx.x * 256 + threadIdx.x;   // < NBFD
  int bf = idx >> 8;
  int b = bf / NF;
  float swx = 0.f, swy = 0.f;
  #pragma unroll
  for (int f = 0; f < NF; ++f){
    swx += g_bfsum[b*NF + f];
    swy += g_bfsum[NBF + b*NF + f];
  }
  float wx = 1.0f / (1.0f + swx * (1.0f/(NF*NN)));
  float wy = 1.0f / (1.0f + swy * (1.0f/(NF*NN)));
  float mnx = INFINITY, mxx = -INFINITY, mny = INFINITY, mxy = -INFINITY;
  #pragma unroll
  for (int c = 0; c < 32; ++c){
    mnx = fminf(mnx, g_pmn[0][(size_t)c*NBFD + idx]);
    mxx = fmaxf(mxx, g_pmx[0][(size_t)c*NBFD + idx]);
    mny = fminf(mny, g_pmn[1][(size_t)c*NBFD + idx]);
    mxy = fmaxf(mxy, g_pmx[1][(size_t)c*NBFD + idx]);
  }
  float sx = wx / (mxx - mnx), sy = wy / (mxy - mny);
  g_coef[idx] = make_float4(sx, -sx * mnx, sy, -sy * mny);
}

// K5: out = sx*xb + ox + sy*yb + oy from the L3-hot bf16 copies (halves
// read bytes vs fp32 x,y). One thread per 8 elements; flat 5120-block grid.
__global__ void __launch_bounds__(256) k_out(floatx4* __restrict__ out){
  size_t e0 = ((size_t)blockIdx.x * 256 + threadIdx.x) * 8;  // elem index
  int bf = (int)(e0 >> 19);                   // NN*NDM = 2^19
  int d0 = (int)(e0 & 255);
  short8 xv = *(const short8*)&g_xb[e0];
  short8 yv = *(const short8*)&g_yb[e0];
  const float4* cf = &g_coef[bf*256 + d0];
  floatx4 o0, o1;
  #pragma unroll
  for (int j = 0; j < 4; ++j){
    float4 c = cf[j];
    o0[j] = c.x * bf2f(xv[j]) + c.y + c.z * bf2f(yv[j]) + c.w;
  }
  #pragma unroll
  for (int j = 0; j < 4; ++j){
    float4 c = cf[4 + j];
    o1[j] = c.x * bf2f(xv[4 + j]) + c.y + c.z * bf2f(yv[4 + j]) + c.w;
  }
  __builtin_nontemporal_store(o0, &out[e0 >> 2]);
  __builtin_nontemporal_store(o1, &out[(e0 >> 2) + 1]);
}

extern "C" void kernel_launch(void* const* d_in, const int* in_sizes, int n_in,
                              void* d_out, int out_size, void* d_ws, size_t ws_size,
                              hipStream_t stream) {
  const float* x = (const float*)d_in[0];
  const float* y = (const float*)d_in[1];
  (void)d_ws; (void)ws_size; (void)in_sizes; (void)n_in; (void)out_size;

  k_prep  <<<dim3(1280), dim3(256), 0, stream>>>(x, y);
  k_gemm  <<<dim3(1280), dim3(256), 0, stream>>>();
  k_weight<<<dim3(160),  dim3(256), 0, stream>>>();
  k_coef  <<<dim3(20),   dim3(256), 0, stream>>>();
  k_out   <<<dim3(5120), dim3(256), 0, stream>>>((floatx4*)d_out);
}